// Round 10
// baseline (85.768 us; speedup 1.0000x reference)
//
#include <hip/hip_runtime.h>

// ---------------------------------------------------------------------------
// maskselfattention: B=2, S=2048, D=1024, H=16, hd=64
// convert x,W to bf16 (W transposed) -> ONE fused QKV GEMM (z-fused: A tile
// staged once, 3 B tiles; 128x64 tile, BK=64, swizzled LDS) writing Q,K
// [b][h][s][64] and V transposed [b][h][64][s] -> causal flash attention:
// 2-wave blocks, wave owns 32 q-rows (2 frags) of one 64-row q-tile, K/V
// staged in LDS (dbuf, swizzled) -- 16 ds_read_b128/iter now feed 32 q-rows
// (DS traffic per q halved vs r9). Swapped QK^T (S^T) -> packed b64 P-stores;
// fixed-reference-max softmax; row-sum via all-ones MFMA.
// ---------------------------------------------------------------------------

typedef unsigned short u16;
typedef unsigned long long u64;
typedef __bf16 bf16x8 __attribute__((ext_vector_type(8)));
typedef __bf16 bf16x4 __attribute__((ext_vector_type(4)));
typedef float f32x4 __attribute__((ext_vector_type(4)));
typedef u16 u16x8 __attribute__((ext_vector_type(8)));

#define NB 2
#define NS 2048
#define ND 1024
#define NH 16
#define HD 64

__device__ __forceinline__ u16 f2bf(float f) {
    unsigned int u = __float_as_uint(f);
    unsigned int r = u + 0x7fffu + ((u >> 16) & 1u);
    return (u16)(r >> 16);
}

__device__ __forceinline__ f32x4 mfma16(bf16x8 a, bf16x8 b, f32x4 c) {
    return __builtin_amdgcn_mfma_f32_16x16x32_bf16(a, b, c, 0, 0, 0);
}

__device__ __forceinline__ void gl_lds16(const void* g, void* l) {
    __builtin_amdgcn_global_load_lds(
        (const __attribute__((address_space(1))) unsigned int*)g,
        (__attribute__((address_space(3))) unsigned int*)l, 16, 0, 0);
}

// swizzled LDS fragment read from a [rows][128B] tile
__device__ __forceinline__ bf16x8 ldsw(const u16* base, int row, int colb) {
    return *(const bf16x8*)((const char*)base + row * 128 +
                            (colb ^ ((row & 7) << 4)));
}

// --- x (fp32) -> xb (bf16) -------------------------------------------------
__global__ __launch_bounds__(256) void convx_k(const float* __restrict__ x,
                                               u16* __restrict__ xb) {
    int i = (blockIdx.x * 256 + threadIdx.x) * 8;
    const float4* p = (const float4*)(x + i);
    float4 a = p[0], c = p[1];
    u16x8 r;
    r[0] = f2bf(a.x); r[1] = f2bf(a.y); r[2] = f2bf(a.z); r[3] = f2bf(a.w);
    r[4] = f2bf(c.x); r[5] = f2bf(c.y); r[6] = f2bf(c.z); r[7] = f2bf(c.w);
    *(u16x8*)(xb + i) = r;
}

// --- W [k][n] fp32 -> Wt [z][n][k] bf16 ------------------------------------
__global__ __launch_bounds__(256) void convw_k(const float* __restrict__ wq,
                                               const float* __restrict__ wk,
                                               const float* __restrict__ wv,
                                               u16* __restrict__ wt) {
    __shared__ float tile[32][33];
    const int z = blockIdx.z;
    const float* W = (z == 0) ? wq : (z == 1) ? wk : wv;
    const int k0 = blockIdx.x * 32, n0 = blockIdx.y * 32;
    const int tx = threadIdx.x & 31, ty = threadIdx.x >> 5;
#pragma unroll
    for (int rr = 0; rr < 32; rr += 8)
        tile[ty + rr][tx] = W[(size_t)(k0 + ty + rr) * ND + n0 + tx];
    __syncthreads();
    u16* dst = wt + (size_t)z * ND * ND;
#pragma unroll
    for (int rr = 0; rr < 32; rr += 8)
        dst[(size_t)(n0 + ty + rr) * ND + k0 + tx] = f2bf(tile[tx][ty + rr]);
}

// --- z-fused QKV GEMM ------------------------------------------------------
// Grid (32,16): m0 = bx*128, n0 = by*64. 256 threads = 4 waves (2M x 2N),
// wave owns 64x32 per z. BK=64. A staged once + 3 B tiles per K-step.
__global__ __launch_bounds__(256) void qkv_gemm_k(const u16* __restrict__ xb,
                                                  const u16* __restrict__ wt,
                                                  u16* __restrict__ qh,
                                                  u16* __restrict__ kh,
                                                  u16* __restrict__ vt) {
    __shared__ u16 At[128 * 64];     // 16 KiB
    __shared__ u16 Bt[3][64 * 64];   // 3 x 8 KiB
    const int m0 = blockIdx.x * 128;
    const int n0 = blockIdx.y * 64;
    const int t = threadIdx.x;
    const int lane = t & 63;
    const int wv = t >> 6;
    const int wm = (wv >> 1) * 64, wn = (wv & 1) * 32;
    const int fr = lane & 15;
    const int ks = lane >> 4;

    f32x4 acc[3][4][2] = {};

    for (int kt = 0; kt < ND; kt += 64) {
#pragma unroll
        for (int c = 0; c < 4; c++) {
            const int L = c * 4096 + t * 16;
            const int row = L >> 7;
            const int cb = (L & 127) ^ ((row & 7) << 4);
            gl_lds16((const char*)xb + (size_t)(m0 + row) * 2048 + kt * 2 + cb,
                     (char*)At + L);
        }
#pragma unroll
        for (int z = 0; z < 3; z++)
#pragma unroll
            for (int c = 0; c < 2; c++) {
                const int L = c * 4096 + t * 16;
                const int row = L >> 7;  // 0..63
                const int cb = (L & 127) ^ ((row & 7) << 4);
                gl_lds16((const char*)wt + (size_t)z * (ND * ND * 2) +
                             (size_t)(n0 + row) * 2048 + kt * 2 + cb,
                         (char*)&Bt[z][0] + L);
            }
        __syncthreads();

        bf16x8 fa[4][2];
#pragma unroll
        for (int i = 0; i < 4; i++)
#pragma unroll
            for (int c = 0; c < 2; c++)
                fa[i][c] = ldsw(At, wm + i * 16 + fr, c * 64 + ks * 16);

#pragma unroll
        for (int z = 0; z < 3; z++) {
            bf16x8 fb[2][2];
#pragma unroll
            for (int j = 0; j < 2; j++)
#pragma unroll
                for (int c = 0; c < 2; c++)
                    fb[j][c] =
                        ldsw(&Bt[z][0], wn + j * 16 + fr, c * 64 + ks * 16);
            if (z < 2) {
#pragma unroll
                for (int i = 0; i < 4; i++)
#pragma unroll
                    for (int j = 0; j < 2; j++)
#pragma unroll
                        for (int c = 0; c < 2; c++)
                            acc[z][i][j] =
                                mfma16(fa[i][c], fb[j][c], acc[z][i][j]);
            } else {
#pragma unroll
                for (int i = 0; i < 4; i++)
#pragma unroll
                    for (int j = 0; j < 2; j++)
#pragma unroll
                        for (int c = 0; c < 2; c++)
                            acc[z][i][j] =
                                mfma16(fb[j][c], fa[i][c], acc[z][i][j]);
            }
        }
        __syncthreads();
    }

#pragma unroll
    for (int z = 0; z < 2; z++) {
        u16* dst = (z == 0) ? qh : kh;
#pragma unroll
        for (int i = 0; i < 4; i++)
#pragma unroll
            for (int j = 0; j < 2; j++)
#pragma unroll
                for (int r = 0; r < 4; r++) {
                    int mg = m0 + wm + i * 16 + ks * 4 + r;
                    int ng = n0 + wn + j * 16 + fr;
                    int b = mg >> 11, s = mg & 2047;
                    int hh = ng >> 6, dd = ng & 63;
                    dst[(((size_t)b * NH + hh) * NS + s) * HD + dd] =
                        f2bf(acc[z][i][j][r]);
                }
    }
#pragma unroll
    for (int i = 0; i < 4; i++)
#pragma unroll
        for (int j = 0; j < 2; j++)
#pragma unroll
            for (int r = 0; r < 4; r++) {
                int ng = n0 + wn + j * 16 + ks * 4 + r;  // d-dim
                int mg = m0 + wm + i * 16 + fr;          // s-dim
                int b = mg >> 11, s = mg & 2047;
                int hh = ng >> 6, dd = ng & 63;
                vt[(((size_t)b * NH + hh) * HD + dd) * NS + s] =
                    f2bf(acc[2][i][j][r]);
            }
}

// --- causal flash attention ------------------------------------------------
// Grid 1024 x 128 threads (2 waves). bh = blk&31 (XCD-affine), q-tile =
// 31 - blk>>5 (heavy tiles dispatched first). Wave wv owns 32 q-rows
// (2 fragments): q0 = tile*64 + wv*32. KVBLK=64, LDS dbuf (swizzled).
// 16 ds_read_b128 per iter feed all 32 q-rows. Swapped QK^T: sc[kf][qf] =
// S^T fragment; packed b64 P-stores; fixed-ref-max softmax p=exp(s/8-8);
// l via all-ones MFMA. 40 KB LDS -> 4 blocks/CU (8 waves/CU).

__device__ __forceinline__ void stage_kv(const u16* __restrict__ K,
                                         const u16* __restrict__ V, int kv0,
                                         u16* Kl, u16* Vl, int t) {
#pragma unroll
    for (int c = 0; c < 4; c++) {
        const int L = c * 2048 + t * 16;
        const int row = L >> 7;
        const int cb = (L & 127) ^ ((row & 7) << 4);
        gl_lds16((const char*)K + (size_t)(kv0 + row) * 128 + cb,
                 (char*)Kl + L);
        gl_lds16((const char*)V + (size_t)row * (NS * 2) + kv0 * 2 + cb,
                 (char*)Vl + L);
    }
}

// sc = S^T fragments for 2 q-fragments; write P[q][kv] as packed b64
template <bool MASKED>
__device__ __forceinline__ void sm_pxT(const f32x4 sc[4][2], u16* pl, int kv0,
                                       int q0, int fr, int ks) {
#pragma unroll
    for (int qf = 0; qf < 2; qf++) {
        const int row = qf * 16 + fr;
        const int qg = q0 + row;
#pragma unroll
        for (int kf = 0; kf < 4; kf++) {
            const int kvb = kv0 + kf * 16 + ks * 4;
            bf16x4 pb;
#pragma unroll
            for (int r = 0; r < 4; r++) {
                float s = sc[kf][qf][r];
                if (MASKED && (kvb + r > qg)) s = -3.0e38f;
                pb[r] = (__bf16)__expf(fmaf(s, 0.125f, -8.0f));
            }
            const u64 w = __builtin_bit_cast(u64, pb);
            const int chunk = (2 * kf + (ks >> 1)) ^ (row & 7);
            *(u64*)((char*)pl + row * 128 + (chunk << 4) + ((ks & 1) << 3)) =
                w;
        }
    }
}

__global__ __launch_bounds__(128, 2) void attn_k(const u16* __restrict__ qh,
                                                 const u16* __restrict__ kh,
                                                 const u16* __restrict__ vt,
                                                 float* __restrict__ out) {
    const int t = threadIdx.x, lane = t & 63, wv = t >> 6;  // wv in {0,1}
    const int fr = lane & 15, ks = lane >> 4;
    const int bh = blockIdx.x & 31;
    const int tile = 31 - (int)(blockIdx.x >> 5);  // heavy first
    const int b = bh >> 4, h = bh & 15;
    const int q0 = tile * 64 + wv * 32;
    const int nIt = tile + 1;
    const u16* Q = qh + (size_t)bh * NS * HD;
    const u16* K = kh + (size_t)bh * NS * HD;
    const u16* V = vt + (size_t)bh * HD * NS;

    __shared__ u16 Kl[2][64 * 64];
    __shared__ u16 Vl[2][64 * 64];
    __shared__ u16 P[2][32 * 64];
    u16* pl = &P[wv][0];

    bf16x8 fq[2][2];
#pragma unroll
    for (int qf = 0; qf < 2; qf++)
#pragma unroll
        for (int sl = 0; sl < 2; sl++)
            fq[qf][sl] = *(const bf16x8*)&Q[(q0 + qf * 16 + fr) * HD +
                                            sl * 32 + ks * 8];

    u16x8 ob;
#pragma unroll
    for (int j = 0; j < 8; j++) ob[j] = 0x3F80;  // bf16 1.0
    const bf16x8 ones = __builtin_bit_cast(bf16x8, ob);

    f32x4 o[2][4] = {};
    f32x4 l[2] = {};

    stage_kv(K, V, 0, &Kl[0][0], &Vl[0][0], t);
    __syncthreads();

    for (int it = 0; it < nIt; ++it) {
        const int cur = it & 1;
        const int kv0 = it * 64;
        if (it + 1 < nIt)
            stage_kv(K, V, kv0 + 64, &Kl[cur ^ 1][0], &Vl[cur ^ 1][0], t);

        bf16x8 fk[4][2];
#pragma unroll
        for (int kf = 0; kf < 4; kf++)
#pragma unroll
            for (int sl = 0; sl < 2; sl++)
                fk[kf][sl] = ldsw(&Kl[cur][0], kf * 16 + fr,
                                  sl * 64 + ks * 16);

        // swapped QK^T: sc[kf][qf] = S^T fragment (kv rows, q cols)
        f32x4 sc[4][2] = {};
#pragma unroll
        for (int kf = 0; kf < 4; kf++)
#pragma unroll
            for (int qf = 0; qf < 2; qf++) {
                sc[kf][qf] = mfma16(fk[kf][0], fq[qf][0], sc[kf][qf]);
                sc[kf][qf] = mfma16(fk[kf][1], fq[qf][1], sc[kf][qf]);
            }

        if (it == nIt - 1)
            sm_pxT<true>(sc, pl, kv0, q0, fr, ks);
        else
            sm_pxT<false>(sc, pl, kv0, q0, fr, ks);

        bf16x8 fv[4][2];
#pragma unroll
        for (int j = 0; j < 4; j++)
#pragma unroll
            for (int s2 = 0; s2 < 2; s2++)
                fv[j][s2] = ldsw(&Vl[cur][0], j * 16 + fr,
                                 s2 * 64 + ks * 16);

#pragma unroll
        for (int qf = 0; qf < 2; qf++) {
            bf16x8 pa[2];
#pragma unroll
            for (int s2 = 0; s2 < 2; s2++) {
                const int row = qf * 16 + fr;
                const int c = (s2 * 4 + ks) ^ (row & 7);
                pa[s2] =
                    *(const bf16x8*)((const char*)pl + row * 128 + (c << 4));
            }
            l[qf] = mfma16(pa[0], ones, l[qf]);
            l[qf] = mfma16(pa[1], ones, l[qf]);
#pragma unroll
            for (int j = 0; j < 4; j++)
#pragma unroll
                for (int s2 = 0; s2 < 2; s2++)
                    o[qf][j] = mfma16(pa[s2], fv[j][s2], o[qf][j]);
        }

        __syncthreads();
    }

#pragma unroll
    for (int qf = 0; qf < 2; qf++) {
        float rl[4];
#pragma unroll
        for (int r = 0; r < 4; r++) rl[r] = 1.0f / l[qf][r];
#pragma unroll
        for (int j = 0; j < 4; j++)
#pragma unroll
            for (int r = 0; r < 4; r++) {
                const int qg = q0 + qf * 16 + ks * 4 + r;
                out[((size_t)b * NS + qg) * ND + h * HD + j * 16 + fr] =
                    o[qf][j][r] * rl[r];
            }
    }
}

extern "C" void kernel_launch(void* const* d_in, const int* in_sizes, int n_in,
                              void* d_out, int out_size, void* d_ws,
                              size_t ws_size, hipStream_t stream) {
    const float* x = (const float*)d_in[0];
    const float* wq = (const float*)d_in[1];
    const float* wk = (const float*)d_in[2];
    const float* wvp = (const float*)d_in[3];
    float* out = (float*)d_out;

    char* w8 = (char*)d_ws;
    u16* xb = (u16*)(w8);                      // 8 MiB
    u16* wt = (u16*)(w8 + ((size_t)8 << 20));  // 6 MiB
    u16* qh = (u16*)(w8 + ((size_t)14 << 20));
    u16* kh = (u16*)(w8 + ((size_t)22 << 20));
    u16* vt = (u16*)(w8 + ((size_t)30 << 20));

    convx_k<<<(NB * NS * ND) / (256 * 8), 256, 0, stream>>>(x, xb);
    convw_k<<<dim3(ND / 32, ND / 32, 3), 256, 0, stream>>>(wq, wk, wvp, wt);
    qkv_gemm_k<<<dim3((NB * NS) / 128, ND / 64), 256, 0, stream>>>(
        xb, wt, qh, kh, vt);
    attn_k<<<1024, 128, 0, stream>>>(qh, kh, vt, out);
}